// Round 8
// baseline (405.551 us; speedup 1.0000x reference)
//
#include <hip/hip_runtime.h>
#include <math.h>

#define NG 4096
#define M 50
#define KTOP 30
#define H 32
#define F_IN 128
#define EPG 400          // edges per graph (M * DEG)
#define PADE 768         // CSR rows padded to multiples of 8 (sum <= 400+50*7)
#define E_TOTAL (NG * EPG)
#define DLAT 97
#define LATS 100         // padded stride for lat tile (keeps 16B alignment)
#define NTHREADS 256
#define WS_C1P 0         // ws: C1w padded [16][100], rows 16B-aligned
#define XH 64            // x staged in two K-halves of 64 (halves LDS for xs)

// fast tanh: 1 - 2/(e^{2x}+1). abs err ~1e-6; layers 1-3 only (layer 4 =
// sort key uses exact tanhf).
__device__ __forceinline__ float fast_tanh(float x) {
    x = fminf(fmaxf(x, -15.f), 15.f);
    float e = __expf(2.f * x);
    return 1.f - 2.f / (e + 1.f);
}

// ---- prep: pad C1w rows 97 -> 100 floats (16B-aligned rows, pad = 0) ----
__global__ void prep_kernel(const float* __restrict__ C1w, float* __restrict__ ws) {
    const int tid = blockIdx.x * blockDim.x + threadIdx.x;
    if (tid < 1600) {
        int c = tid / 100, d = tid - c * 100;
        ws[WS_C1P + tid] = (d < DLAT) ? C1w[c * DLAT + d] : 0.f;
    }
}

// -------- GCN matmul core (all-LDS operands) ------------------------------
// R5 (confirmed, -17us): W in LDS, row-major -> b32 lane-consecutive reads
// (conflict-free); x reads are b128 broadcasts. R7 LESSON: transposed-W b64
// = structural 4-way bank conflict (even stride pairs lanes j/j+16); pk_fma
// asm defeats the scheduler -- reverted.
// R8: UNROLL 4 (was 2). The unroll-2 cap was an artifact of the 64-VGPR
// budget; residency is pinned at 4 blocks/CU (R1-R3), so at 16 waves/CU the
// 2048-reg pool (m69) allows 128 VGPR/thread free -> launch_bounds(256,2).
template <int KIN>
__device__ __forceinline__ void gcn_matmul_acc(const float* hin, int istride,
                                               const float* W,
                                               const int* rows, float* acc, int j) {
#pragma unroll 4
    for (int k4 = 0; k4 < KIN / 4; k4++) {
        const float w0 = W[(4 * k4 + 0) * H + j];
        const float w1 = W[(4 * k4 + 1) * H + j];
        const float w2 = W[(4 * k4 + 2) * H + j];
        const float w3 = W[(4 * k4 + 3) * H + j];
#pragma unroll
        for (int r = 0; r < 7; r++) {
            const float4 xv = *(const float4*)(hin + rows[r] * istride + 4 * k4);
            acc[r] += xv.x * w0 + xv.y * w1 + xv.z * w2 + xv.w * w3;
        }
    }
}

// full matmul for layers 2/3: tn[i][j] = dinv[i] * sum_k hin[i*istride+k]*W[k*H+j].
// PRE-SCALED by dinv[row]: the agg then needs no per-edge norms at all.
// thread (iset = tid>>5, j = tid&31) owns rows {iset, iset+8, ..., iset+48};
// row 49 recomputed by 6 threads (clamp) -- branch-free body.
template <int KIN>
__device__ __forceinline__ void gcn_matmul(const float* hin, int istride,
                                           const float* W,
                                           float (*tb)[H], const float* dinv, int tid) {
    const int j = tid & 31, iset = tid >> 5;
    float acc[7];
    int rows[7];
#pragma unroll
    for (int r = 0; r < 7; r++) {
        acc[r] = 0.f;
        int i = iset + r * 8;
        rows[r] = (i >= M) ? (M - 1) : i;
    }
    gcn_matmul_acc<KIN>(hin, istride, W, rows, acc, j);
#pragma unroll
    for (int r = 0; r < 7; r++) {
        int i = iset + r * 8;
        if (i < M) tb[i][j] = acc[r] * dinv[i];
    }
}

// aggregation + bias + tanh on PRE-SCALED tn: acc = tn[i] + sum_s tn[s];
// out = tanh(dinv[i]*acc + b). R8: rows padded to multiples of 8; ONE u64
// load gives 8 packed u8 src ids feeding TWO independent accumulator chains
// -> 2x the in-flight LDS depth in this latency-bound phase. Pad slots hold
// sentinel src=M (tn[M][*]==0): branch-free.
__device__ __forceinline__ void gcn_agg(const float (*tbuf)[H], const float* __restrict__ b,
                                        float (*lat)[LATS], int col0,
                                        const float* dinv, const unsigned short* csr_off,
                                        const unsigned char* csr_src, int tid) {
    const int j = tid & 31, iset = tid >> 5;
    for (int i = iset; i < M; i += 8) {
        float acc = tbuf[i][j];                      // self (prescaled)
        float acc2 = 0.f;
        int e0 = csr_off[i], e1 = csr_off[i + 1];
        for (int e = e0; e < e1; e += 8) {
            const unsigned long long sp = *(const unsigned long long*)(csr_src + e);
            acc  += tbuf[(unsigned)(sp)       & 255][j];
            acc  += tbuf[(unsigned)(sp >> 8)  & 255][j];
            acc  += tbuf[(unsigned)(sp >> 16) & 255][j];
            acc  += tbuf[(unsigned)(sp >> 24) & 255][j];
            acc2 += tbuf[(unsigned)(sp >> 32) & 255][j];
            acc2 += tbuf[(unsigned)(sp >> 40) & 255][j];
            acc2 += tbuf[(unsigned)(sp >> 48) & 255][j];
            acc2 += tbuf[(unsigned)(sp >> 56)      ][j];
        }
        lat[i][col0 + j] = fast_tanh((acc + acc2) * dinv[i] + b[j]);
    }
}

struct Post {                                      // 3392 B tail (phase union)
    float pbuf[16][15];
    union {
        struct { float z1[16][KTOP]; unsigned char ord[52]; } a;
        struct { float z2[352]; float red[256]; } b;
    } u;
};

// R8: (256,2) -> VGPR cap 128. Residency is PINNED at 4 blocks/CU = 16
// waves/CU (R1-R3 nulls), and 16 waves x 128 VGPR = the 2048-reg pool (m69)
// -- so raising the cap cannot reduce residency. TRIPWIRES: VGPR <= 128,
// WRITE_SIZE ~128KB (ballooning = spill = revert to (256,4)+unroll2).
__global__ __launch_bounds__(NTHREADS, 2)
void dgcnn_kernel(const float* __restrict__ x, const int* __restrict__ eidx,
                  const float* __restrict__ ws,
                  const float* __restrict__ W0, const float* __restrict__ b0,
                  const float* __restrict__ W1, const float* __restrict__ b1,
                  const float* __restrict__ W2, const float* __restrict__ b2,
                  const float* __restrict__ W3, const float* __restrict__ b3,
                  const float* __restrict__ C1b,
                  const float* __restrict__ C2w, const float* __restrict__ C2b,
                  const float* __restrict__ L1w, const float* __restrict__ L1b,
                  const float* __restrict__ L2w, const float* __restrict__ L2b,
                  float* __restrict__ out) {
    // LDS plan (R6 layout + PADE 768):
    //   Big 20992 + TP 6528 + w12u 10240 + csr_src 768 + csr_off 104
    //   + degi 200 + dinv 200 = ~39.1 KB; 4-block residency class.
    __shared__ __align__(16) union Big {
        struct { float xs[M][XH]; float w0h[XH][H]; } p1;  // 20992 B
        float lat[M][LATS];                                // 20000 B
    } big;
    __shared__ __align__(16) union TP {
        float tbuf[M + 1][H];              //  6528 B, dies after layer-4 agg
        Post post;                         //  3392 B, born at sort
    } tp;
    __shared__ __align__(16) union W12U {
        float w[2][H][H];                  //  8192 B: W1, W2 (die layer-3 mm)
        float c2w[32 * 16 * 5];            // 10240 B: conv2 weights (born agg-3)
    } w12u;
    __shared__ __align__(8) unsigned char csr_src[PADE];  // 768 B (u64 loads)
    __shared__ unsigned short csr_off[M + 2];      //   104 B
    __shared__ int   degi[M];                      //   200 B (becomes cursor)
    __shared__ float dinv[M];                      //   200 B

    const int g = blockIdx.x;
    const int tid = threadIdx.x;
    const int nbase = g * M;
    const int ebase = g * EPG;

    // ---- stage x half 0 + W0 half 0 + W1/W2 -> LDS (bulk coalesced) ----
    {
        const float4* xg4 = (const float4*)(x + (size_t)nbase * F_IN);
        float4* xs4 = (float4*)big.p1.xs;
        for (int idx = tid; idx < M * XH / 4; idx += NTHREADS) {
            int i = idx >> 4, q = idx & 15;          // 16 float4 per xs row
            xs4[idx] = xg4[i * 32 + q];              // 32 float4 per x row
        }
        float4* w0f = (float4*)big.p1.w0h;           // W0 rows 0..63
        const float4* w0g = (const float4*)W0;
        for (int idx = tid; idx < 512; idx += NTHREADS)
            w0f[idx] = w0g[idx];
        float4* wf = (float4*)w12u.w;                // W1 | W2, 512 float4
        for (int idx = tid; idx < 512; idx += NTHREADS) {
            const float4* srcp = (idx < 256) ? ((const float4*)W1 + idx)
                                             : ((const float4*)W2 + (idx - 256));
            wf[idx] = *srcp;
        }
    }
    // ---- init: degrees + sentinel-fill padded CSR src (0x32 = row M) ----
    if (tid < M) degi[tid] = 1;
    for (int idx = tid; idx < PADE / 4; idx += NTHREADS)
        ((unsigned*)csr_src)[idx] = 0x32323232u;
    __syncthreads();
    for (int e = tid; e < EPG; e += NTHREADS) {
        int d = eidx[E_TOTAL + ebase + e] - nbase;
        atomicAdd(&degi[d], 1);
    }
    __syncthreads();
    // ---- dinv + padded-CSR offsets (wave-0 shuffle scan); cursor=degi ----
    // rows padded to multiples of 8 (R8 dual-chain agg).
    if (tid < M) dinv[tid] = rsqrtf((float)degi[tid]);
    if (tid < 64) {
        int cnt  = (tid < M) ? (degi[tid] - 1) : 0;
        int cntp = (cnt + 7) & ~7;
        int incl = cntp;
#pragma unroll
        for (int off = 1; off < 64; off <<= 1) {
            int nv = __shfl_up(incl, off);
            if (tid >= off) incl += nv;
        }
        if (tid < M) {
            csr_off[tid] = (unsigned short)(incl - cntp);
            degi[tid] = incl - cntp;
        }
        if (tid == M - 1) csr_off[M] = (unsigned short)incl;
    }
    __syncthreads();
    // ---- CSR fill + layer-1 matmul half 0 (independent; one barrier) ----
    const int j1 = tid & 31, iset1 = tid >> 5;
    float acc1[7];
    int rows1[7];
#pragma unroll
    for (int r = 0; r < 7; r++) {
        acc1[r] = 0.f;
        int i = iset1 + r * 8;
        rows1[r] = (i >= M) ? (M - 1) : i;
    }
    for (int e = tid; e < EPG; e += NTHREADS) {
        int s = eidx[ebase + e] - nbase;
        int d = eidx[E_TOTAL + ebase + e] - nbase;
        int pos = atomicAdd(&degi[d], 1);
        csr_src[pos] = (unsigned char)s;
    }
    gcn_matmul_acc<XH>(&big.p1.xs[0][0], XH, &big.p1.w0h[0][0], rows1, acc1, j1);
    __syncthreads();                     // all reads of xs/w0h half 0 done
    // ---- stage x half 1 + W0 half 1; acc1 stays in registers ----
    {
        const float4* xg4 = (const float4*)(x + (size_t)nbase * F_IN);
        float4* xs4 = (float4*)big.p1.xs;
        for (int idx = tid; idx < M * XH / 4; idx += NTHREADS) {
            int i = idx >> 4, q = idx & 15;
            xs4[idx] = xg4[i * 32 + 16 + q];
        }
        float4* w0f = (float4*)big.p1.w0h;           // W0 rows 64..127
        const float4* w0g = (const float4*)(W0 + XH * H);
        for (int idx = tid; idx < 512; idx += NTHREADS)
            w0f[idx] = w0g[idx];
    }
    __syncthreads();
    gcn_matmul_acc<XH>(&big.p1.xs[0][0], XH, &big.p1.w0h[0][0], rows1, acc1, j1);
#pragma unroll
    for (int r = 0; r < 7; r++) {
        int i = iset1 + r * 8;
        if (i < M) tp.tbuf[i][j1] = acc1[r] * dinv[i];
    }
    if (tid < H) tp.tbuf[M][tid] = 0.f;  // sentinel row for CSR pad slots
    __syncthreads();                     // xs/w0h dead from here; lat live

    // ---- layer 1 agg -> lat[:,0:32]; also zero lat pad cols 97..99 ----
    gcn_agg(tp.tbuf, b0, big.lat, 0, dinv, csr_off, csr_src, tid);
    for (int idx = tid; idx < 3 * M; idx += NTHREADS)
        big.lat[idx / 3][DLAT + idx % 3] = 0.f;     // conv1 reads 100 cols
    __syncthreads();
    // ---- layer 2 (W1 from LDS) ----
    gcn_matmul<H>(&big.lat[0][0], LATS, &w12u.w[0][0][0], tp.tbuf, dinv, tid);
    __syncthreads();
    gcn_agg(tp.tbuf, b1, big.lat, 32, dinv, csr_off, csr_src, tid);
    __syncthreads();
    // ---- layer 3 (W2 from LDS) ----
    gcn_matmul<H>(&big.lat[0][32], LATS, &w12u.w[1][0][0], tp.tbuf, dinv, tid);
    __syncthreads();                     // w12u.w dead after this barrier
    // ---- layer 3 agg + C2w -> LDS stage (independent; same phase) ----
    gcn_agg(tp.tbuf, b2, big.lat, 64, dinv, csr_off, csr_src, tid);
    {
        float4* cf = (float4*)w12u.c2w;              // 640 float4 = 10240 B
        const float4* cg = (const float4*)C2w;
        for (int idx = tid; idx < 640; idx += NTHREADS)
            cf[idx] = cg[idx];
    }
    __syncthreads();
    // ---- layer 4 (H -> 1): exact tanhf (sort key) ----
    if (tid < M) {
        float acc = 0.f;
        for (int k = 0; k < H; k++) acc += big.lat[tid][64 + k] * W3[k];
        tp.tbuf[tid][0] = acc * dinv[tid];
    }
    __syncthreads();
    if (tid < M) {
        float acc = tp.tbuf[tid][0], acc2 = 0.f;
        int e0 = csr_off[tid], e1 = csr_off[tid + 1];
        for (int e = e0; e < e1; e += 8) {
            const unsigned long long sp = *(const unsigned long long*)(csr_src + e);
            acc  += tp.tbuf[(unsigned)(sp)       & 255][0]
                  + tp.tbuf[(unsigned)(sp >> 8)  & 255][0]
                  + tp.tbuf[(unsigned)(sp >> 16) & 255][0]
                  + tp.tbuf[(unsigned)(sp >> 24) & 255][0];
            acc2 += tp.tbuf[(unsigned)(sp >> 32) & 255][0]
                  + tp.tbuf[(unsigned)(sp >> 40) & 255][0]
                  + tp.tbuf[(unsigned)(sp >> 48) & 255][0]
                  + tp.tbuf[(unsigned)(sp >> 56)      ][0];
        }
        big.lat[tid][96] = tanhf((acc + acc2) * dinv[tid] + b3[0]);
    }
    __syncthreads();                     // tbuf dead from here; post live

    // ---- sort-pool: stable descending rank over lat[:,96] ----
    if (tid < M) {
        float v = big.lat[tid][96];
        int r = 0;
        for (int jj = 0; jj < M; jj++) {
            float vj = big.lat[jj][96];
            r += (vj > v) || (vj == v && jj < tid);
        }
        tp.post.u.a.ord[r] = (unsigned char)tid;
    }
    __syncthreads();

    // ---- Conv1d(1,16,97,stride 97) + ReLU, float4 over d ----
    // t=idx>>4: 16 lanes share a row -> LDS b128 broadcast; C1P rows (ws)
    // are 100 floats = 400 B (16B-aligned), pad cols = 0.
    for (int idx = tid; idx < 16 * KTOP; idx += NTHREADS) {
        int t = idx >> 4, c = idx & 15;
        const float4* row = (const float4*)big.lat[tp.post.u.a.ord[t]];
        const float4* cw  = (const float4*)(ws + WS_C1P + c * LATS);
        float acc = 0.f;
#pragma unroll 5
        for (int q = 0; q < LATS / 4; q++) {
            float4 rv = row[q], wv = cw[q];
            acc += rv.x * wv.x + rv.y * wv.y + rv.z * wv.z + rv.w * wv.w;
        }
        tp.post.u.a.z1[c][t] = fmaxf(acc + C1b[c], 0.f);
    }
    __syncthreads();

    // ---- MaxPool1d(2,2) -> pbuf (outside inner union) ----
    for (int idx = tid; idx < 16 * 15; idx += NTHREADS) {
        int c = idx / 15, t = idx - c * 15;
        tp.post.pbuf[c][t] = fmaxf(tp.post.u.a.z1[c][2 * t],
                                   tp.post.u.a.z1[c][2 * t + 1]);
    }
    __syncthreads();

    // ---- Conv1d(16,32,5) + ReLU, flatten f = o*11 + t (C2w from LDS) ----
    // 2 independent accs (even/odd i) halve the serial FMA chain.
    for (int idx = tid; idx < 352; idx += NTHREADS) {
        int o = idx / 11, t = idx - o * 11;
        float a0 = C2b[o], a1 = 0.f;
        for (int i = 0; i < 16; i += 2) {
#pragma unroll
            for (int k = 0; k < 5; k++) {
                a0 += tp.post.pbuf[i][t + k]     * w12u.c2w[(o * 16 + i) * 5 + k];
                a1 += tp.post.pbuf[i + 1][t + k] * w12u.c2w[(o * 16 + i + 1) * 5 + k];
            }
        }
        tp.post.u.b.z2[idx] = fmaxf(a0 + a1, 0.f);
    }
    __syncthreads();

    // ---- Dense 352 -> 128 + ReLU (split over 2 halves; coalesced L1w) ----
    // 4 independent accumulators: breaks the single FMA dep chain and lets
    // more coalesced L1w loads pipeline.
    {
        int jj = tid & 127, half = tid >> 7;
        int f0 = half * 176;
        const float* Lp = L1w + (size_t)f0 * 128 + jj;
        const float* zp = tp.post.u.b.z2 + f0;
        float a0 = 0.f, a1 = 0.f, a2 = 0.f, a3 = 0.f;
#pragma unroll 2
        for (int f = 0; f < 176; f += 4) {
            a0 += zp[f]     * Lp[(f)     * 128];
            a1 += zp[f + 1] * Lp[(f + 1) * 128];
            a2 += zp[f + 2] * Lp[(f + 2) * 128];
            a3 += zp[f + 3] * Lp[(f + 3) * 128];
        }
        float acc = (a0 + a1) + (a2 + a3) + ((half == 0) ? L1b[jj] : 0.f);
        tp.post.u.b.red[tid] = acc;
    }
    __syncthreads();
    // ---- fuse ReLU + Dense 128 -> 1 ----
    if (tid < 128)
        tp.post.u.b.red[tid] =
            fmaxf(tp.post.u.b.red[tid] + tp.post.u.b.red[tid + 128], 0.f)
            * L2w[tid];
    __syncthreads();
    if (tid < 64) {
        float v = tp.post.u.b.red[tid] + tp.post.u.b.red[tid + 64];
#pragma unroll
        for (int off = 32; off >= 1; off >>= 1)
            v += __shfl_down(v, off);
        if (tid == 0) out[g] = v + L2b[0];
    }
}

extern "C" void kernel_launch(void* const* d_in, const int* in_sizes, int n_in,
                              void* d_out, int out_size, void* d_ws, size_t ws_size,
                              hipStream_t stream) {
    const float* x    = (const float*)d_in[0];
    const int*   eidx = (const int*)d_in[1];
    // d_in[2] (batch) unused: graphs are contiguous equal-size blocks
    float* ws = (float*)d_ws;
    prep_kernel<<<7, 256, 0, stream>>>((const float*)d_in[11], ws);
    dgcnn_kernel<<<NG, NTHREADS, 0, stream>>>(
        x, eidx, ws,
        (const float*)d_in[3],  (const float*)d_in[4],
        (const float*)d_in[5],  (const float*)d_in[6],
        (const float*)d_in[7],  (const float*)d_in[8],
        (const float*)d_in[9],  (const float*)d_in[10],
        (const float*)d_in[12],
        (const float*)d_in[13], (const float*)d_in[14],
        (const float*)d_in[15], (const float*)d_in[16],
        (const float*)d_in[17], (const float*)d_in[18],
        (float*)d_out);
}

// Round 9
// 356.585 us; speedup vs baseline: 1.1373x; 1.1373x over previous
//
#include <hip/hip_runtime.h>
#include <math.h>

#define NG 4096
#define M 50
#define KTOP 30
#define H 32
#define F_IN 128
#define EPG 400          // edges per graph (M * DEG)
#define PADE 552         // EPG + M*3: CSR rows padded to multiples of 4
#define E_TOTAL (NG * EPG)
#define DLAT 97
#define LATS 100         // padded stride for lat tile (keeps 16B alignment)
#define NTHREADS 256
#define WS_C1P 0         // ws: C1w padded [16][100], rows 16B-aligned
#define XH 64            // x staged in two K-halves of 64 (halves LDS for xs)

// fast tanh: 1 - 2/(e^{2x}+1). abs err ~1e-6; layers 1-3 only (layer 4 =
// sort key uses exact tanhf).
__device__ __forceinline__ float fast_tanh(float x) {
    x = fminf(fmaxf(x, -15.f), 15.f);
    float e = __expf(2.f * x);
    return 1.f - 2.f / (e + 1.f);
}

// ---- prep: pad C1w rows 97 -> 100 floats (16B-aligned rows, pad = 0) ----
__global__ void prep_kernel(const float* __restrict__ C1w, float* __restrict__ ws) {
    const int tid = blockIdx.x * blockDim.x + threadIdx.x;
    if (tid < 1600) {
        int c = tid / 100, d = tid - c * 100;
        ws[WS_C1P + tid] = (d < DLAT) ? C1w[c * DLAT + d] : 0.f;
    }
}

// -------- GCN matmul core (all-LDS operands, unroll-2) --------------------
// R5 (confirmed, -17us): W in LDS row-major -> b32 lane-consecutive reads
// (conflict-free); x reads are b128 broadcasts.
// R7 LESSON: transposed-W b64 / pk_fma asm -> bank conflicts + scheduler
// defeat (-33us). R8 LESSON: unroll 4 + launch_bounds(256,2) -> residency
// DROP (arg2 min waves/EU is the SPI residency grant; keep (256,4)).
// UNROLL 2 EXACTLY (prior-session r10 spill lesson).
template <int KIN>
__device__ __forceinline__ void gcn_matmul_acc(const float* hin, int istride,
                                               const float* W,
                                               const int* rows, float* acc, int j) {
#pragma unroll 2
    for (int k4 = 0; k4 < KIN / 4; k4++) {
        const float w0 = W[(4 * k4 + 0) * H + j];
        const float w1 = W[(4 * k4 + 1) * H + j];
        const float w2 = W[(4 * k4 + 2) * H + j];
        const float w3 = W[(4 * k4 + 3) * H + j];
#pragma unroll
        for (int r = 0; r < 7; r++) {
            const float4 xv = *(const float4*)(hin + rows[r] * istride + 4 * k4);
            acc[r] += xv.x * w0 + xv.y * w1 + xv.z * w2 + xv.w * w3;
        }
    }
}

// full matmul for layers 2/3: tn[i][j] = dinv[i] * sum_k hin[i*istride+k]*W[k*H+j].
// PRE-SCALED by dinv[row]: the agg then needs no per-edge norms at all.
// thread (iset = tid>>5, j = tid&31) owns rows {iset, iset+8, ..., iset+48};
// row 49 recomputed by 6 threads (clamp) -- branch-free body.
template <int KIN>
__device__ __forceinline__ void gcn_matmul(const float* hin, int istride,
                                           const float* W,
                                           float (*tb)[H], const float* dinv, int tid) {
    const int j = tid & 31, iset = tid >> 5;
    float acc[7];
    int rows[7];
#pragma unroll
    for (int r = 0; r < 7; r++) {
        acc[r] = 0.f;
        int i = iset + r * 8;
        rows[r] = (i >= M) ? (M - 1) : i;
    }
    gcn_matmul_acc<KIN>(hin, istride, W, rows, acc, j);
#pragma unroll
    for (int r = 0; r < 7; r++) {
        int i = iset + r * 8;
        if (i < M) tb[i][j] = acc[r] * dinv[i];
    }
}

// aggregation + bias + tanh on PRE-SCALED tn: acc = tn[i] + sum_s tn[s];
// out = tanh(dinv[i]*acc + b). Padded CSR rows are multiples of 4; pad slots
// hold sentinel src=M (tn[M][*]==0), so the body is branch-free.
__device__ __forceinline__ void gcn_agg(const float (*tbuf)[H], const float* __restrict__ b,
                                        float (*lat)[LATS], int col0,
                                        const float* dinv, const unsigned short* csr_off,
                                        const unsigned char* csr_src, int tid) {
    const int j = tid & 31, iset = tid >> 5;
    for (int i = iset; i < M; i += 8) {
        float acc = tbuf[i][j];                      // self (prescaled)
        int e0 = csr_off[i], e1 = csr_off[i + 1];
        for (int e = e0; e < e1; e += 4) {
            unsigned sp = *(const unsigned*)(csr_src + e);
            acc += tbuf[sp & 255][j];
            acc += tbuf[(sp >> 8) & 255][j];
            acc += tbuf[(sp >> 16) & 255][j];
            acc += tbuf[sp >> 24][j];
        }
        lat[i][col0 + j] = fast_tanh(acc * dinv[i] + b[j]);
    }
}

struct Post {                                      // 3392 B tail (phase union)
    float pbuf[16][15];
    union {
        struct { float z1[16][KTOP]; unsigned char ord[52]; } a;
        struct { float z2[352]; float red[256]; } b;
    } u;
};

// (256,4): keep -- R8 proved arg2 is the SPI residency grant (4/EU = the
// 42% plateau); (256,2) dropped residency and cost +48us. The (256,4)
// VGPR ceiling is 512/4 = 128, NOT 64 -- R9 spends ~24 of that headroom
// on T14 register prefetch of the half-1 tiles.
__global__ __launch_bounds__(NTHREADS, 4)
void dgcnn_kernel(const float* __restrict__ x, const int* __restrict__ eidx,
                  const float* __restrict__ ws,
                  const float* __restrict__ W0, const float* __restrict__ b0,
                  const float* __restrict__ W1, const float* __restrict__ b1,
                  const float* __restrict__ W2, const float* __restrict__ b2,
                  const float* __restrict__ W3, const float* __restrict__ b3,
                  const float* __restrict__ C1b,
                  const float* __restrict__ C2w, const float* __restrict__ C2b,
                  const float* __restrict__ L1w, const float* __restrict__ L1b,
                  const float* __restrict__ L2w, const float* __restrict__ L2b,
                  float* __restrict__ out) {
    // LDS plan (R6 layout, best known = 229us):
    //   Big 20992 + TP 6528 + w12u 10240 + csr_src 552 + csr_off 104
    //   + degi 200 + dinv 200 = ~38.8 KB (reported 38912).
    // R9: half-1 (x cols 64..127 + W0 rows 64..127) is PREFETCHED INTO
    // REGISTERS at kernel start (issued alongside half-0 staging, drained
    // by the first barrier's vmcnt wait) and written to LDS after the
    // matmul-0 barrier -- the formerly exposed global staging phase
    // between matmul-0 and matmul-1 becomes a pure LDS-write blip.
    // Rationale: the 4 resident blocks are phase-SYNCHRONIZED (identical
    // durations), so serial memory phases are never hidden by cross-block
    // overlap -- they must be removed from the critical path (R5 mechanism).
    __shared__ __align__(16) union Big {
        struct { float xs[M][XH]; float w0h[XH][H]; } p1;  // 20992 B
        float lat[M][LATS];                                // 20000 B
    } big;
    __shared__ __align__(16) union TP {
        float tbuf[M + 1][H];              //  6528 B, dies after layer-4 agg
        Post post;                         //  3392 B, born at sort
    } tp;
    __shared__ __align__(16) union W12U {
        float w[2][H][H];                  //  8192 B: W1, W2 (die layer-3 mm)
        float c2w[32 * 16 * 5];            // 10240 B: conv2 weights (born agg-3)
    } w12u;
    __shared__ unsigned char csr_src[PADE];        //   552 B
    __shared__ unsigned short csr_off[M + 2];      //   104 B
    __shared__ int   degi[M];                      //   200 B (becomes cursor)
    __shared__ float dinv[M];                      //   200 B

    const int g = blockIdx.x;
    const int tid = threadIdx.x;
    const int nbase = g * M;
    const int ebase = g * EPG;

    // ---- stage x half 0 + W0 half 0 + W1/W2 -> LDS (bulk coalesced),
    //      and ISSUE half-1 prefetch into registers (T14) ----
    float4 xr0, xr1, xr2, xr3 = {0.f, 0.f, 0.f, 0.f}, wr0, wr1;
    {
        const float4* xg4 = (const float4*)(x + (size_t)nbase * F_IN);
        float4* xs4 = (float4*)big.p1.xs;
        for (int idx = tid; idx < M * XH / 4; idx += NTHREADS) {
            int i = idx >> 4, q = idx & 15;          // 16 float4 per xs row
            xs4[idx] = xg4[i * 32 + q];              // 32 float4 per x row
        }
        float4* w0f = (float4*)big.p1.w0h;           // W0 rows 0..63
        const float4* w0g = (const float4*)W0;
        for (int idx = tid; idx < 512; idx += NTHREADS)
            w0f[idx] = w0g[idx];
        float4* wf = (float4*)w12u.w;                // W1 | W2, 512 float4
        for (int idx = tid; idx < 512; idx += NTHREADS) {
            const float4* srcp = (idx < 256) ? ((const float4*)W1 + idx)
                                             : ((const float4*)W2 + (idx - 256));
            wf[idx] = *srcp;
        }
        // half-1 prefetch: 800 float4 of x (cols 64..127) + 512 float4 of
        // W0 rows 64..127, held in registers until the matmul-0 barrier.
        {
            int i0 = tid >> 4,          q0 = tid & 15;
            int i1 = (tid + 256) >> 4,  q1 = (tid + 256) & 15;
            int i2 = (tid + 512) >> 4,  q2 = (tid + 512) & 15;
            xr0 = xg4[i0 * 32 + 16 + q0];
            xr1 = xg4[i1 * 32 + 16 + q1];
            xr2 = xg4[i2 * 32 + 16 + q2];
            if (tid < 32) {
                int i3 = (tid + 768) >> 4, q3 = (tid + 768) & 15;
                xr3 = xg4[i3 * 32 + 16 + q3];
            }
            const float4* w0g1 = (const float4*)(W0 + XH * H);
            wr0 = w0g1[tid];
            wr1 = w0g1[tid + 256];
        }
    }
    // ---- init: degrees + sentinel-fill padded CSR src (0x32 = row M) ----
    if (tid < M) degi[tid] = 1;
    for (int idx = tid; idx < PADE / 4; idx += NTHREADS)
        ((unsigned*)csr_src)[idx] = 0x32323232u;
    __syncthreads();
    for (int e = tid; e < EPG; e += NTHREADS) {
        int d = eidx[E_TOTAL + ebase + e] - nbase;
        atomicAdd(&degi[d], 1);
    }
    __syncthreads();
    // ---- dinv + padded-CSR offsets (wave-0 shuffle scan); cursor=degi ----
    if (tid < M) dinv[tid] = rsqrtf((float)degi[tid]);
    if (tid < 64) {
        int cnt  = (tid < M) ? (degi[tid] - 1) : 0;
        int cntp = (cnt + 3) & ~3;
        int incl = cntp;
#pragma unroll
        for (int off = 1; off < 64; off <<= 1) {
            int nv = __shfl_up(incl, off);
            if (tid >= off) incl += nv;
        }
        if (tid < M) {
            csr_off[tid] = (unsigned short)(incl - cntp);
            degi[tid] = incl - cntp;
        }
        if (tid == M - 1) csr_off[M] = (unsigned short)incl;
    }
    __syncthreads();
    // ---- CSR fill + layer-1 matmul half 0 (independent; one barrier) ----
    const int j1 = tid & 31, iset1 = tid >> 5;
    float acc1[7];
    int rows1[7];
#pragma unroll
    for (int r = 0; r < 7; r++) {
        acc1[r] = 0.f;
        int i = iset1 + r * 8;
        rows1[r] = (i >= M) ? (M - 1) : i;
    }
    for (int e = tid; e < EPG; e += NTHREADS) {
        int s = eidx[ebase + e] - nbase;
        int d = eidx[E_TOTAL + ebase + e] - nbase;
        int pos = atomicAdd(&degi[d], 1);
        csr_src[pos] = (unsigned char)s;
    }
    gcn_matmul_acc<XH>(&big.p1.xs[0][0], XH, &big.p1.w0h[0][0], rows1, acc1, j1);
    __syncthreads();                     // all reads of xs/w0h half 0 done
    // ---- half-1: registers -> LDS (prefetched at kernel start) ----
    {
        float4* xs4 = (float4*)big.p1.xs;
        xs4[tid]       = xr0;
        xs4[tid + 256] = xr1;
        xs4[tid + 512] = xr2;
        if (tid < 32) xs4[tid + 768] = xr3;
        float4* w0f = (float4*)big.p1.w0h;           // W0 rows 64..127
        w0f[tid]       = wr0;
        w0f[tid + 256] = wr1;
    }
    __syncthreads();
    gcn_matmul_acc<XH>(&big.p1.xs[0][0], XH, &big.p1.w0h[0][0], rows1, acc1, j1);
#pragma unroll
    for (int r = 0; r < 7; r++) {
        int i = iset1 + r * 8;
        if (i < M) tp.tbuf[i][j1] = acc1[r] * dinv[i];
    }
    if (tid < H) tp.tbuf[M][tid] = 0.f;  // sentinel row for CSR pad slots
    __syncthreads();                     // xs/w0h dead from here; lat live

    // ---- layer 1 agg -> lat[:,0:32]; also zero lat pad cols 97..99 ----
    gcn_agg(tp.tbuf, b0, big.lat, 0, dinv, csr_off, csr_src, tid);
    for (int idx = tid; idx < 3 * M; idx += NTHREADS)
        big.lat[idx / 3][DLAT + idx % 3] = 0.f;     // conv1 reads 100 cols
    __syncthreads();
    // ---- layer 2 (W1 from LDS) ----
    gcn_matmul<H>(&big.lat[0][0], LATS, &w12u.w[0][0][0], tp.tbuf, dinv, tid);
    __syncthreads();
    gcn_agg(tp.tbuf, b1, big.lat, 32, dinv, csr_off, csr_src, tid);
    __syncthreads();
    // ---- layer 3 (W2 from LDS) ----
    gcn_matmul<H>(&big.lat[0][32], LATS, &w12u.w[1][0][0], tp.tbuf, dinv, tid);
    __syncthreads();                     // w12u.w dead after this barrier
    // ---- layer 3 agg + C2w -> LDS stage (independent; same phase) ----
    gcn_agg(tp.tbuf, b2, big.lat, 64, dinv, csr_off, csr_src, tid);
    {
        float4* cf = (float4*)w12u.c2w;              // 640 float4 = 10240 B
        const float4* cg = (const float4*)C2w;
        for (int idx = tid; idx < 640; idx += NTHREADS)
            cf[idx] = cg[idx];
    }
    __syncthreads();
    // ---- layer 4 (H -> 1): exact tanhf (sort key) ----
    if (tid < M) {
        float acc = 0.f;
        for (int k = 0; k < H; k++) acc += big.lat[tid][64 + k] * W3[k];
        tp.tbuf[tid][0] = acc * dinv[tid];
    }
    __syncthreads();
    if (tid < M) {
        float acc = tp.tbuf[tid][0];
        int e0 = csr_off[tid], e1 = csr_off[tid + 1];
        for (int e = e0; e < e1; e += 4) {
            unsigned sp = *(const unsigned*)(csr_src + e);
            acc += tp.tbuf[sp & 255][0] + tp.tbuf[(sp >> 8) & 255][0]
                 + tp.tbuf[(sp >> 16) & 255][0] + tp.tbuf[sp >> 24][0];
        }
        big.lat[tid][96] = tanhf(acc * dinv[tid] + b3[0]);
    }
    __syncthreads();                     // tbuf dead from here; post live

    // ---- sort-pool: stable descending rank over lat[:,96] ----
    if (tid < M) {
        float v = big.lat[tid][96];
        int r = 0;
        for (int jj = 0; jj < M; jj++) {
            float vj = big.lat[jj][96];
            r += (vj > v) || (vj == v && jj < tid);
        }
        tp.post.u.a.ord[r] = (unsigned char)tid;
    }
    __syncthreads();

    // ---- Conv1d(1,16,97,stride 97) + ReLU, float4 over d ----
    // t=idx>>4: 16 lanes share a row -> LDS b128 broadcast; C1P rows (ws)
    // are 100 floats = 400 B (16B-aligned), pad cols = 0.
    for (int idx = tid; idx < 16 * KTOP; idx += NTHREADS) {
        int t = idx >> 4, c = idx & 15;
        const float4* row = (const float4*)big.lat[tp.post.u.a.ord[t]];
        const float4* cw  = (const float4*)(ws + WS_C1P + c * LATS);
        float acc = 0.f;
#pragma unroll 5
        for (int q = 0; q < LATS / 4; q++) {
            float4 rv = row[q], wv = cw[q];
            acc += rv.x * wv.x + rv.y * wv.y + rv.z * wv.z + rv.w * wv.w;
        }
        tp.post.u.a.z1[c][t] = fmaxf(acc + C1b[c], 0.f);
    }
    __syncthreads();

    // ---- MaxPool1d(2,2) -> pbuf (outside inner union) ----
    for (int idx = tid; idx < 16 * 15; idx += NTHREADS) {
        int c = idx / 15, t = idx - c * 15;
        tp.post.pbuf[c][t] = fmaxf(tp.post.u.a.z1[c][2 * t],
                                   tp.post.u.a.z1[c][2 * t + 1]);
    }
    __syncthreads();

    // ---- Conv1d(16,32,5) + ReLU, flatten f = o*11 + t (C2w from LDS) ----
    // 2 independent accs (even/odd i) halve the serial FMA chain.
    for (int idx = tid; idx < 352; idx += NTHREADS) {
        int o = idx / 11, t = idx - o * 11;
        float a0 = C2b[o], a1 = 0.f;
        for (int i = 0; i < 16; i += 2) {
#pragma unroll
            for (int k = 0; k < 5; k++) {
                a0 += tp.post.pbuf[i][t + k]     * w12u.c2w[(o * 16 + i) * 5 + k];
                a1 += tp.post.pbuf[i + 1][t + k] * w12u.c2w[(o * 16 + i + 1) * 5 + k];
            }
        }
        tp.post.u.b.z2[idx] = fmaxf(a0 + a1, 0.f);
    }
    __syncthreads();

    // ---- Dense 352 -> 128 + ReLU (split over 2 halves; coalesced L1w) ----
    // 4 independent accumulators: breaks the single FMA dep chain and lets
    // more coalesced L1w loads pipeline.
    {
        int jj = tid & 127, half = tid >> 7;
        int f0 = half * 176;
        const float* Lp = L1w + (size_t)f0 * 128 + jj;
        const float* zp = tp.post.u.b.z2 + f0;
        float a0 = 0.f, a1 = 0.f, a2 = 0.f, a3 = 0.f;
#pragma unroll 2
        for (int f = 0; f < 176; f += 4) {
            a0 += zp[f]     * Lp[(f)     * 128];
            a1 += zp[f + 1] * Lp[(f + 1) * 128];
            a2 += zp[f + 2] * Lp[(f + 2) * 128];
            a3 += zp[f + 3] * Lp[(f + 3) * 128];
        }
        float acc = (a0 + a1) + (a2 + a3) + ((half == 0) ? L1b[jj] : 0.f);
        tp.post.u.b.red[tid] = acc;
    }
    __syncthreads();
    // ---- fuse ReLU + Dense 128 -> 1 ----
    if (tid < 128)
        tp.post.u.b.red[tid] =
            fmaxf(tp.post.u.b.red[tid] + tp.post.u.b.red[tid + 128], 0.f)
            * L2w[tid];
    __syncthreads();
    if (tid < 64) {
        float v = tp.post.u.b.red[tid] + tp.post.u.b.red[tid + 64];
#pragma unroll
        for (int off = 32; off >= 1; off >>= 1)
            v += __shfl_down(v, off);
        if (tid == 0) out[g] = v + L2b[0];
    }
}

extern "C" void kernel_launch(void* const* d_in, const int* in_sizes, int n_in,
                              void* d_out, int out_size, void* d_ws, size_t ws_size,
                              hipStream_t stream) {
    const float* x    = (const float*)d_in[0];
    const int*   eidx = (const int*)d_in[1];
    // d_in[2] (batch) unused: graphs are contiguous equal-size blocks
    float* ws = (float*)d_ws;
    prep_kernel<<<7, 256, 0, stream>>>((const float*)d_in[11], ws);
    dgcnn_kernel<<<NG, NTHREADS, 0, stream>>>(
        x, eidx, ws,
        (const float*)d_in[3],  (const float*)d_in[4],
        (const float*)d_in[5],  (const float*)d_in[6],
        (const float*)d_in[7],  (const float*)d_in[8],
        (const float*)d_in[9],  (const float*)d_in[10],
        (const float*)d_in[12],
        (const float*)d_in[13], (const float*)d_in[14],
        (const float*)d_in[15], (const float*)d_in[16],
        (const float*)d_in[17], (const float*)d_in[18],
        (float*)d_out);
}